// Round 7
// baseline (82.116 us; speedup 1.0000x reference)
//
#include <hip/hip_runtime.h>

// Geometry (fixed): imgs [2,1,128,128,128] f32, flow [2,3,128,128,128] f32
#define VOL   4194304
#define FLOWN 12582912
#define SMCNT 12484608.0f   // 2*3*127*128*128
#define WIN_INV (1.0f / 729.0f)

__device__ __forceinline__ void block_reduce_atomic(float v, float* red, float* dst) {
#pragma unroll
    for (int off = 32; off; off >>= 1) v += __shfl_down(v, off);
    if ((threadIdx.x & 63) == 0) red[threadIdx.x >> 6] = v;
    __syncthreads();
    if (threadIdx.x == 0) atomicAdd(dst, red[0] + red[1] + red[2] + red[3]);
}

struct __align__(16) NccLds {
    float wst[4][5][16][24];  // per-WAVE W-sums, transposed [wv][c][w][rr]; 96B rows
    float hst[4][5][16][16];  // per-plane H-sums [plane-in-group][c][w][h]
};
// 4*5*16*24*4 + 4*5*16*16*4 = 30720 + 20480 = 51200 B -> 3 blocks/CU

// sliding 9-window over 12 inputs -> 4 outputs, transposed write at row wrr
#define WSLIDE(c, X0,X1,X2,X3,X4,X5,X6,X7,X8,X9,X10,X11)                   \
    {                                                                      \
        const float o0 = X0+X1+X2+X3+X4+X5+X6+X7+X8;                       \
        const float o1 = o0 - X0 + X9;                                     \
        const float o2 = o1 - X1 + X10;                                    \
        const float o3 = o2 - X2 + X11;                                    \
        L->wst[wv][c][wq4 + 0][wrr] = o0;                                  \
        L->wst[wv][c][wq4 + 1][wrr] = o1;                                  \
        L->wst[wv][c][wq4 + 2][wrr] = o2;                                  \
        L->wst[wv][c][wq4 + 3][wrr] = o3;                                  \
    }

#define EMIT {                                                             \
        const float cross = S[4] - S[0] * S[1] * WIN_INV;                  \
        const float iv    = S[2] - S[0] * S[0] * WIN_INV;                  \
        const float jv    = S[3] - S[1] * S[1] * WIN_INV;                  \
        local += cross * cross / (iv * jv + 1e-5f);                       \
    }

// Block = (n, 16h x 16w tile, 16-deep d-chunk). 4 waves each own one d-plane
// per iteration (4 planes/iter x 6 iters = 24 planes). W->H is wave-local
// (lgkmcnt sync only); one barrier pair per 4-plane exchange.
__device__ void ncc_block(const float* __restrict__ I, const float* __restrict__ J,
                          float* __restrict__ acc, NccLds* L, float* red, int nb) {
    const int wt = nb & 7, ht = (nb >> 3) & 7, dc = (nb >> 6) & 7, n = nb >> 9;
    const int w0 = wt << 4, h0 = ht << 4, d0 = dc << 4;
    const int tid = threadIdx.x;
    const int wv   = tid >> 6;
    const int lane = tid & 63;
    const int th = tid & 15, tw = (tid >> 4) & 15;   // owned output (h,w)
    const int hw = (lane >> 2) & 15, hq = lane & 3;  // H-phase geometry

    float hist[5][9];
#pragma unroll
    for (int c = 0; c < 5; ++c)
#pragma unroll
        for (int k = 0; k < 9; ++k) hist[c][k] = 0.f;
    float S[5] = {0.f, 0.f, 0.f, 0.f, 0.f};
    float local = 0.f;
    const long nbase = (long)n * 2097152;

    float4 Ri0[2], Ri1[2], Ri2[2], Rj0[2], Rj1[2], Rj2[2];

    auto load_plane = [&](int s4) {
        const int dp = d0 - 4 + s4 + wv;
        const bool v = (unsigned)dp < 128u;
#pragma unroll
        for (int r = 0; r < 2; ++r) {
            const float4 z4 = make_float4(0.f, 0.f, 0.f, 0.f);
            Ri0[r] = Ri1[r] = Ri2[r] = Rj0[r] = Rj1[r] = Rj2[r] = z4;
            const int item = lane + (r << 6);
            if (v && item < 96) {
                const int rr = item >> 2, q4 = (item & 3) << 2;
                const int gh = h0 - 4 + rr, gwb = w0 + q4 - 4;
                if ((unsigned)gh < 128u) {
                    const float* Ip = I + nbase + (long)dp * 16384 + gh * 128 + gwb;
                    const float* Jp = J + nbase + (long)dp * 16384 + gh * 128 + gwb;
                    if (gwb >= 0)   { Ri0[r] = *(const float4*)Ip;       Rj0[r] = *(const float4*)Jp; }
                    Ri1[r] = *(const float4*)(Ip + 4);                   Rj1[r] = *(const float4*)(Jp + 4);
                    if (gwb <= 116) { Ri2[r] = *(const float4*)(Ip + 8); Rj2[r] = *(const float4*)(Jp + 8); }
                }
            }
        }
    };

    load_plane(0);
    for (int pp = 0; pp < 6; ++pp) {
        const int dpw = d0 - 4 + 4 * pp + wv;
        const bool vpl = (unsigned)dpw < 128u;
        // ---- W phase (wave-local): regs -> wst[wv] transposed ----
        if (vpl) {
#pragma unroll
            for (int r = 0; r < 2; ++r) {
                const int item = lane + (r << 6);
                if (item < 96) {
                    const int wrr = item >> 2, wq4 = (item & 3) << 2;
                    const float4 i0 = Ri0[r], i1 = Ri1[r], i2 = Ri2[r];
                    const float4 j0 = Rj0[r], j1 = Rj1[r], j2 = Rj2[r];
                    WSLIDE(0, i0.x,i0.y,i0.z,i0.w, i1.x,i1.y,i1.z,i1.w, i2.x,i2.y,i2.z,i2.w)
                    WSLIDE(1, j0.x,j0.y,j0.z,j0.w, j1.x,j1.y,j1.z,j1.w, j2.x,j2.y,j2.z,j2.w)
                    WSLIDE(2, i0.x*i0.x,i0.y*i0.y,i0.z*i0.z,i0.w*i0.w,
                              i1.x*i1.x,i1.y*i1.y,i1.z*i1.z,i1.w*i1.w,
                              i2.x*i2.x,i2.y*i2.y,i2.z*i2.z,i2.w*i2.w)
                    WSLIDE(3, j0.x*j0.x,j0.y*j0.y,j0.z*j0.z,j0.w*j0.w,
                              j1.x*j1.x,j1.y*j1.y,j1.z*j1.z,j1.w*j1.w,
                              j2.x*j2.x,j2.y*j2.y,j2.z*j2.z,j2.w*j2.w)
                    WSLIDE(4, i0.x*j0.x,i0.y*j0.y,i0.z*j0.z,i0.w*j0.w,
                              i1.x*j1.x,i1.y*j1.y,i1.z*j1.z,i1.w*j1.w,
                              i2.x*j2.x,i2.y*j2.y,i2.z*j2.z,i2.w*j2.w)
                }
            }
        }
        // wave-local producer->consumer fence (cross-lane via LDS).
        // sched_barrier(0) pins the W-writes/H-reads around the waitcnt
        // (rule #18: hipcc may hoist past inline-asm waitcnt).
        asm volatile("s_waitcnt lgkmcnt(0)" ::: "memory");
        __builtin_amdgcn_sched_barrier(0);
        // ---- H phase (wave-local): wst[wv] -> hst[wv], sliding along rr ----
        if (vpl) {
#pragma unroll
            for (int c = 0; c < 5; ++c) {
                const float* sp = &L->wst[wv][c][hw][hq << 2];
                const float4 a0 = *(const float4*)sp;
                const float4 a1 = *(const float4*)(sp + 4);
                const float4 a2 = *(const float4*)(sp + 8);
                const float o0 = a0.x+a0.y+a0.z+a0.w+a1.x+a1.y+a1.z+a1.w+a2.x;
                const float o1 = o0 - a0.x + a2.y;
                const float o2 = o1 - a0.y + a2.z;
                const float o3 = o2 - a0.z + a2.w;
                *(float4*)&L->hst[wv][c][hw][hq << 2] = make_float4(o0, o1, o2, o3);
            }
        }
        // issue next iteration's global loads early (latency hides under final)
        if (pp < 5) load_plane(4 * (pp + 1));
        __syncthreads();
        // ---- final: 4-plane exchange into per-thread D-ring ----
        float p[4][5];
#pragma unroll
        for (int q = 0; q < 4; ++q) {
            const bool v = (unsigned)(d0 - 4 + 4 * pp + q) < 128u;
#pragma unroll
            for (int c = 0; c < 5; ++c)
                p[q][c] = v ? L->hst[q][c][tw][th] : 0.f;
        }
#pragma unroll
        for (int c = 0; c < 5; ++c) S[c] += p[0][c] - hist[c][8];
        if (pp >= 2) EMIT
#pragma unroll
        for (int c = 0; c < 5; ++c) S[c] += p[1][c] - hist[c][7];
        if (pp >= 2) EMIT
#pragma unroll
        for (int c = 0; c < 5; ++c) S[c] += p[2][c] - hist[c][6];
        if (pp >= 2) EMIT
#pragma unroll
        for (int c = 0; c < 5; ++c) S[c] += p[3][c] - hist[c][5];
        if (pp >= 2) EMIT
#pragma unroll
        for (int c = 0; c < 5; ++c) {
            hist[c][8] = hist[c][4]; hist[c][7] = hist[c][3];
            hist[c][6] = hist[c][2]; hist[c][5] = hist[c][1];
            hist[c][4] = hist[c][0];
            hist[c][3] = p[0][c];    hist[c][2] = p[1][c];
            hist[c][1] = p[2][c];    hist[c][0] = p[3][c];
        }
        __syncthreads();
    }
    block_reduce_atomic(local, red, &acc[0]);
}

__device__ void mse_block(const float4* __restrict__ a, const float4* __restrict__ b,
                          float* __restrict__ acc, float* red, int mb) {
    float local = 0.f;
    for (int i = mb * 256 + threadIdx.x; i < VOL / 4; i += 512 * 256) {
        const float4 x = a[i], y = b[i];
        const float d0 = x.x - y.x, d1 = x.y - y.y, d2 = x.z - y.z, d3 = x.w - y.w;
        local += d0 * d0 + d1 * d1 + d2 * d2 + d3 * d3;
    }
    block_reduce_atomic(local, red, &acc[1]);
}

__device__ void smooth_block(const float4* __restrict__ s,
                             float* __restrict__ acc, float* red, int sb) {
    float local = 0.f;
    for (int f = sb * 256 + threadIdx.x; f < FLOWN / 4; f += 2048 * 256) {
        const int w4 = f & 31, h = (f >> 5) & 127, d = (f >> 12) & 127;
        const float4 v = s[f];
        const float t1 = v.y - v.x, t2 = v.z - v.y, t3 = v.w - v.z;
        local += t1 * t1 + t2 * t2 + t3 * t3;
        if (w4 < 31) {
            const float nx = ((const float*)s)[4 * f + 4];
            const float t = nx - v.w;
            local += t * t;
        }
        if (h < 127) {
            const float4 nh = s[f + 32];
            const float u0 = nh.x - v.x, u1 = nh.y - v.y, u2 = nh.z - v.z, u3 = nh.w - v.w;
            local += u0 * u0 + u1 * u1 + u2 * u2 + u3 * u3;
        }
        if (d < 127) {
            const float4 nd = s[f + 4096];
            const float u0 = nd.x - v.x, u1 = nd.y - v.y, u2 = nd.z - v.z, u3 = nd.w - v.w;
            local += u0 * u0 + u1 * u1 + u2 * u2 + u3 * u3;
        }
    }
    block_reduce_atomic(local, red, &acc[2]);
}

// Interleaved: g%7<2 -> ncc (1024), else mse (512) / smooth (2048): each CU
// keeps ~1 ncc + ~2 streaming blocks resident, soaking HBM throughout.
__global__ __launch_bounds__(256, 3) void fused_k(const float* __restrict__ imgsA,
                                                  const float* __restrict__ recon,
                                                  const float* __restrict__ warped,
                                                  const float* __restrict__ flow,
                                                  float* __restrict__ acc) {
    __shared__ NccLds Lsh;
    __shared__ float red[4];
    const int g = blockIdx.x;
    const int r7 = g % 7, q7 = g / 7;
    if (r7 < 2) {
        ncc_block(warped, imgsA, acc, &Lsh, red, q7 * 2 + r7);
    } else {
        const int mb = q7 * 5 + (r7 - 2);
        if (mb < 512) mse_block((const float4*)imgsA, (const float4*)recon, acc, red, mb);
        else          smooth_block((const float4*)flow, acc, red, mb - 512);
    }
}

__global__ void fin_k(const float* __restrict__ acc, float* __restrict__ out) {
    if (threadIdx.x == 0) {
        out[0] = 1.0f - acc[0] * (1.0f / (float)VOL);
        out[1] = acc[1] * (1.0f / (float)VOL);
        out[2] = acc[2] * (1.0f / (3.0f * SMCNT));
    }
}

extern "C" void kernel_launch(void* const* d_in, const int* in_sizes, int n_in,
                              void* d_out, int out_size, void* d_ws, size_t ws_size,
                              hipStream_t stream) {
    const float* imgsA  = (const float*)d_in[0];
    const float* recon  = (const float*)d_in[1];
    const float* warped = (const float*)d_in[2];
    const float* flow   = (const float*)d_in[3];
    float* out = (float*)d_out;
    float* acc = (float*)d_ws;

    hipMemsetAsync(d_ws, 0, 16, stream);
    fused_k<<<3584, 256, 0, stream>>>(imgsA, recon, warped, flow, acc);
    fin_k<<<1, 64, 0, stream>>>(acc, out);
}